// Round 4
// baseline (10880.667 us; speedup 1.0000x reference)
//
#include <hip/hip_runtime.h>
#include <cstdint>
#include <cstddef>

#define B_    256
#define T_    128
#define SIG_  64
#define MET_  32
#define H_    256
#define F_    16
#define NCOL  1040   // [i:0..255 | ste:256..511 | c:512..767 | o:768..1023 | fre:1024..1039]
#define TC    16
#define NCHUNK (T_/TC)

__device__ __forceinline__ float hsig(float x) {
    return fminf(fmaxf(x * (1.0f/6.0f) + 0.5f, 0.0f), 1.0f);
}

__device__ __forceinline__ unsigned short f2bf(float f) {
    unsigned int u = __float_as_uint(f);
    unsigned int r = (u + 0x7fffu + ((u >> 16) & 1u)) >> 16;
    return (unsigned short)r;
}

__device__ __forceinline__ float ntload_f(const float* p) {
    return __builtin_nontemporal_load(p);
}
__device__ __forceinline__ float4 ntload_f4(const float* p) {
    float4 v;
    v.x = __builtin_nontemporal_load(p + 0);
    v.y = __builtin_nontemporal_load(p + 1);
    v.z = __builtin_nontemporal_load(p + 2);
    v.w = __builtin_nontemporal_load(p + 3);
    return v;
}

// column order: i(256) | ste(256) | c(256) | o(256) | fre(16)
__device__ __forceinline__ void colmap(int n, int& sec, int& idx) {
    if (n < 256)       { sec = 0; idx = n; }
    else if (n < 512)  { sec = 1; idx = n - 256; }
    else if (n < 768)  { sec = 2; idx = n - 512; }
    else if (n < 1024) { sec = 3; idx = n - 768; }
    else               { sec = 4; idx = n - 1024; }
}

// ---------------------------------------------------------------------------
// Pack weights: Wcat[96][1040] f32, bcat[1040] f32, UT[1040][256] bf16 (U^T)
// ---------------------------------------------------------------------------
__global__ __launch_bounds__(256) void pack_kernel(
    const float* __restrict__ Wis, const float* __restrict__ Wstes, const float* __restrict__ Wfres,
    const float* __restrict__ Wcs, const float* __restrict__ Wos,
    const float* __restrict__ Wim, const float* __restrict__ Wstem, const float* __restrict__ Wfrem,
    const float* __restrict__ Wcm, const float* __restrict__ Wom,
    const float* __restrict__ Ui, const float* __restrict__ Uste, const float* __restrict__ Ufre,
    const float* __restrict__ Uc, const float* __restrict__ Uo,
    const float* __restrict__ bi, const float* __restrict__ bste, const float* __restrict__ bfre,
    const float* __restrict__ bc, const float* __restrict__ bo,
    float* __restrict__ Wcat, float* __restrict__ bcat, unsigned short* __restrict__ UT)
{
    int gtid = blockIdx.x * blockDim.x + threadIdx.x;
    int stride = gridDim.x * blockDim.x;
    const float* Wsig[5] = {Wis, Wstes, Wcs, Wos, Wfres};
    const float* Wmet[5] = {Wim, Wstem, Wcm, Wom, Wfrem};
    const float* Us[5]   = {Ui, Uste, Uc, Uo, Ufre};
    const float* bs[5]   = {bi, bste, bc, bo, bfre};

    for (int i = gtid; i < 96*NCOL; i += stride) {
        int k = i / NCOL, n = i - k*NCOL;
        int sec, idx; colmap(n, sec, idx);
        int secN = (sec == 4) ? F_ : H_;
        float v = (k < 64) ? Wsig[sec][k*secN + idx] : Wmet[sec][(k-64)*secN + idx];
        Wcat[k*NCOL + n] = v;
    }
    for (int n = gtid; n < NCOL; n += stride) {
        int sec, idx; colmap(n, sec, idx);
        bcat[n] = bs[sec][idx];
    }
    for (int i = gtid; i < NCOL*H_; i += stride) {
        int n = i >> 8, k = i & 255;
        int sec, idx; colmap(n, sec, idx);
        int secN = (sec == 4) ? F_ : H_;
        UT[n*H_ + k] = f2bf(Us[sec][k*secN + idx]);
    }
}

// ---------------------------------------------------------------------------
// Phase 1: input projection GEMM for ALL time steps (z = chunk of 16 steps).
// ---------------------------------------------------------------------------
__global__ __launch_bounds__(256) void proj_kernel(
    const float* __restrict__ sig, const float* __restrict__ met,
    const float* __restrict__ Wcat, const float* __restrict__ bcat,
    float* __restrict__ X)
{
    __shared__ float A_s[32][128];
    __shared__ float W_s[32][128];
    int tid = threadIdx.x;
    int c0b = blockIdx.x * 128;
    int m0  = blockIdx.y * 128;
    int t0  = blockIdx.z * 16;
    int r0  = (tid >> 4) * 8;
    int c0t = (tid & 15) * 8;

    float acc[8][8];
    #pragma unroll
    for (int i = 0; i < 8; ++i)
        #pragma unroll
        for (int j = 0; j < 8; ++j) acc[i][j] = 0.0f;

    for (int k0 = 0; k0 < 96; k0 += 32) {
        for (int idx = tid; idx < 32*128; idx += 256) {
            int ml = idx & 127, kk = idx >> 7;
            int m = m0 + ml;
            int b = m >> 4, tl = m & 15;
            int g = b * T_ + t0 + tl;
            int k = k0 + kk;
            float v = (k < 64) ? sig[g*SIG_ + k] : met[g*MET_ + (k - 64)];
            A_s[kk][ml] = v;
        }
        for (int idx = tid; idx < 32*128; idx += 256) {
            int c = idx & 127, kk = idx >> 7;
            int n = c0b + c;
            W_s[kk][c] = (n < NCOL) ? Wcat[(k0+kk)*NCOL + n] : 0.0f;
        }
        __syncthreads();
        #pragma unroll
        for (int kk = 0; kk < 32; ++kk) {
            float4 a0 = *(const float4*)&A_s[kk][r0];
            float4 a1 = *(const float4*)&A_s[kk][r0+4];
            float4 w0 = *(const float4*)&W_s[kk][c0t];
            float4 w1 = *(const float4*)&W_s[kk][c0t+4];
            float av[8] = {a0.x,a0.y,a0.z,a0.w,a1.x,a1.y,a1.z,a1.w};
            float wv[8] = {w0.x,w0.y,w0.z,w0.w,w1.x,w1.y,w1.z,w1.w};
            #pragma unroll
            for (int i = 0; i < 8; ++i)
                #pragma unroll
                for (int j = 0; j < 8; ++j)
                    acc[i][j] = fmaf(av[i], wv[j], acc[i][j]);
        }
        __syncthreads();
    }
    #pragma unroll
    for (int i = 0; i < 8; ++i) {
        int m = m0 + r0 + i;
        int bb = m >> 4, tl = m & 15;
        size_t row = (size_t)bb * T_ + t0 + tl;
        #pragma unroll
        for (int j = 0; j < 8; ++j) {
            int n = c0b + c0t + j;
            if (n < NCOL) X[row*NCOL + n] = acc[i][j] + bcat[n];
        }
    }
}

// ---------------------------------------------------------------------------
// Phase 2: recurrence over ONE chunk of TC=16 steps (chunked dispatches keep
// UT L2-resident — proven in R1; monolithic loses it — proven in R2/R3).
// 1024 threads (16 waves) per block for latency hiding. One block per batch.
// ---------------------------------------------------------------------------
__device__ __forceinline__ float dot8(uint4 u, float4 ha, float4 hb, float acc) {
    acc = fmaf(__uint_as_float(u.x << 16),          ha.x, acc);
    acc = fmaf(__uint_as_float(u.x & 0xffff0000u),  ha.y, acc);
    acc = fmaf(__uint_as_float(u.y << 16),          ha.z, acc);
    acc = fmaf(__uint_as_float(u.y & 0xffff0000u),  ha.w, acc);
    acc = fmaf(__uint_as_float(u.z << 16),          hb.x, acc);
    acc = fmaf(__uint_as_float(u.z & 0xffff0000u),  hb.y, acc);
    acc = fmaf(__uint_as_float(u.w << 16),          hb.z, acc);
    acc = fmaf(__uint_as_float(u.w & 0xffff0000u),  hb.w, acc);
    return acc;
}

__global__ __launch_bounds__(1024) void recur_kernel(
    const float* __restrict__ X, const unsigned short* __restrict__ UT,
    float* __restrict__ h_g, float* __restrict__ Sre_g, float* __restrict__ Sim_g,
    const float* __restrict__ U_a, const float* __restrict__ b_a,
    const float* __restrict__ W_p, const float* __restrict__ b_p,
    const float* __restrict__ fc_w, const float* __restrict__ fc_b,
    float* __restrict__ out, int t0)
{
    __shared__ float h_s[H_];
    __shared__ float pre_s[1024];
    __shared__ float qp[64];          // fre quarter partials: qp[f*4+q]
    __shared__ float cs_s[16], sn_s[16];

    int tid  = threadIdx.x;
    int b    = blockIdx.x;
    int lane = tid & 63;
    int wid  = tid >> 6;
    bool isfre = ((lane & 15) == 15);
    int fq_dot = lane >> 4;           // quarter 0..3 (when isfre)

    // update-phase ownership: j = tid>>2 (h index), f0 = (tid&3)*4 (f range)
    int j  = tid >> 2;
    int f0 = (tid & 3) * 4;

    float Sre[4], Sim[4];
    if (t0 == 0) {
        if (tid < H_) h_s[tid] = 0.0f;
        #pragma unroll
        for (int r = 0; r < 4; ++r) { Sre[r] = 0.0f; Sim[r] = 0.0f; }
    } else {
        if (tid < H_) h_s[tid] = h_g[b*H_ + tid];
        float4 r4 = *(const float4*)(Sre_g + ((size_t)b*H_ + j)*16 + f0);
        float4 i4 = *(const float4*)(Sim_g + ((size_t)b*H_ + j)*16 + f0);
        Sre[0]=r4.x; Sre[1]=r4.y; Sre[2]=r4.z; Sre[3]=r4.w;
        Sim[0]=i4.x; Sim[1]=i4.y; Sim[2]=i4.z; Sim[3]=i4.w;
    }
    if (tid < 16) {
        float ang = (float)tid * 0.39269908169872414f; // 2*pi/16
        cs_s[tid] = cosf(ang);
        sn_s[tid] = sinf(ang);
    }

    float ba_j = b_a[j];
    float4 ua4 = ((const float4*)U_a)[tid & 3];
    const uint4* Ucol = (const uint4*)(UT + (size_t)tid * H_);
    const uint4* Ufre = (const uint4*)(UT + (size_t)(1024 + wid) * H_ + fq_dot * 64);
    const float* Xb = X + ((size_t)b * T_ + t0) * NCOL;

    float hnew = (t0 == 0) ? 0.0f : h_g[b*H_ + j];
    __syncthreads();

    for (int tl = 0; tl < TC; ++tl) {
        const float* xrow = Xb + (size_t)tl * NCOL;

        // ---- dot phase: pre[col=tid] = x + U[:,col] . h ----
        float acc = ntload_f(&xrow[tid]);
        #pragma unroll
        for (int k8 = 0; k8 < 32; ++k8) {
            float4 ha = *(const float4*)&h_s[k8*8];
            float4 hb = *(const float4*)&h_s[k8*8 + 4];
            acc = dot8(Ucol[k8], ha, hb, acc);
        }
        float fa = 0.0f;
        if (isfre) {
            #pragma unroll
            for (int q = 0; q < 8; ++q) {
                float4 ha = *(const float4*)&h_s[fq_dot*64 + q*8];
                float4 hb = *(const float4*)&h_s[fq_dot*64 + q*8 + 4];
                fa = dot8(Ufre[q], ha, hb, fa);
            }
        }
        pre_s[tid] = acc;
        if (isfre) qp[wid*4 + fq_dot] = fa;
        __syncthreads();   // A: pre_s + qp ready; h_s reads done

        // ---- update phase ----
        float xi   = pre_s[j];
        float xste = pre_s[256 + j];
        float xc   = pre_s[512 + j];
        float xo   = pre_s[768 + j];
        float gi   = hsig(xi);
        float gste = hsig(xste);
        float go   = hsig(xo);
        float cc   = gi * tanhf(xc);

        float4 xfre = ntload_f4(&xrow[1024 + f0]);
        float4 q0 = *(const float4*)&qp[(f0+0)*4];
        float4 q1 = *(const float4*)&qp[(f0+1)*4];
        float4 q2 = *(const float4*)&qp[(f0+2)*4];
        float4 q3 = *(const float4*)&qp[(f0+3)*4];
        float fre[4];
        fre[0] = hsig(xfre.x + q0.x + q0.y + q0.z + q0.w);
        fre[1] = hsig(xfre.y + q1.x + q1.y + q1.z + q1.w);
        fre[2] = hsig(xfre.z + q2.x + q2.y + q2.z + q2.w);
        fre[3] = hsig(xfre.w + q3.x + q3.y + q3.z + q3.w);

        int tt1 = (t0 + tl + 1) & 15;
        float Aa = 0.0f;
        #pragma unroll
        for (int r = 0; r < 4; ++r) {
            int idx = (tt1 * (f0 + r)) & 15;
            float dec = gste * fre[r];
            float sre = fmaf(dec, Sre[r], cc * cs_s[idx]);
            float sim = fmaf(dec, Sim[r], cc * sn_s[idx]);
            Sre[r] = sre; Sim[r] = sim;
            Aa = fmaf(fmaf(sre, sre, sim*sim), ((const float*)&ua4)[r], Aa);
        }
        Aa += __shfl_xor(Aa, 1);
        Aa += __shfl_xor(Aa, 2);
        if ((tid & 3) == 0) {
            float a = tanhf(Aa + ba_j);
            hnew = go * a;
            h_s[j] = hnew;
        }
        __syncthreads();   // B: h_s ready for next step; pre_s/qp reads done
    }

    // ---- spill state for next chunk ----
    if ((tid & 3) == 0) h_g[b*H_ + j] = hnew;
    float4 r4, i4;
    r4.x=Sre[0]; r4.y=Sre[1]; r4.z=Sre[2]; r4.w=Sre[3];
    i4.x=Sim[0]; i4.y=Sim[1]; i4.z=Sim[2]; i4.w=Sim[3];
    *(float4*)(Sre_g + ((size_t)b*H_ + j)*16 + f0) = r4;
    *(float4*)(Sim_g + ((size_t)b*H_ + j)*16 + f0) = i4;

    if (t0 + TC == T_) {
        // ---- head: out[b] = (sum_j h[j]*W_p[j] + b_p)*fc_w + fc_b ----
        if ((tid & 3) == 0) pre_s[j] = hnew * W_p[j];
        __syncthreads();
        for (int s = 128; s > 0; s >>= 1) {
            if (tid < s) pre_s[tid] += pre_s[tid + s];
            __syncthreads();
        }
        if (tid == 0) out[b] = (pre_s[0] + b_p[0]) * fc_w[0] + fc_b[0];
    }
}

// ---------------------------------------------------------------------------
extern "C" void kernel_launch(void* const* d_in, const int* in_sizes, int n_in,
                              void* d_out, int out_size, void* d_ws, size_t ws_size,
                              hipStream_t stream) {
    const float* signal = (const float*)d_in[0];
    const float* metmast = (const float*)d_in[1];
    const float* W_i_s   = (const float*)d_in[2];
    const float* W_ste_s = (const float*)d_in[3];
    const float* W_fre_s = (const float*)d_in[4];
    const float* W_c_s   = (const float*)d_in[5];
    const float* W_o_s   = (const float*)d_in[6];
    const float* W_i_m   = (const float*)d_in[7];
    const float* W_ste_m = (const float*)d_in[8];
    const float* W_fre_m = (const float*)d_in[9];
    const float* W_c_m   = (const float*)d_in[10];
    const float* W_o_m   = (const float*)d_in[11];
    const float* U_i   = (const float*)d_in[12];
    const float* b_i   = (const float*)d_in[13];
    const float* U_ste = (const float*)d_in[14];
    const float* b_ste = (const float*)d_in[15];
    const float* U_fre = (const float*)d_in[16];
    const float* b_fre = (const float*)d_in[17];
    const float* U_c   = (const float*)d_in[18];
    const float* b_c   = (const float*)d_in[19];
    const float* U_o   = (const float*)d_in[20];
    const float* b_o   = (const float*)d_in[21];
    const float* U_a   = (const float*)d_in[22];
    const float* b_a   = (const float*)d_in[23];
    const float* W_p   = (const float*)d_in[24];
    const float* b_p   = (const float*)d_in[25];
    const float* fc_w  = (const float*)d_in[26];
    const float* fc_b  = (const float*)d_in[27];
    float* out = (float*)d_out;

    char* ws = (char*)d_ws;
    float*          Wcat = (float*)(ws + 0);                 //  96*1040*4 = 399360
    float*          bcat = (float*)(ws + 399360);            //  1040*4    = 4160
    unsigned short* UT   = (unsigned short*)(ws + 403520);   //  1040*256*2 = 532480
    float*          h_g  = (float*)(ws + 936000);            //  256*256*4 = 262144
    float*          Sre_g= (float*)(ws + 1198144);           //  4194304
    float*          Sim_g= (float*)(ws + 5392448);           //  4194304
    float*          X    = (float*)(ws + 9586752);           //  256*128*1040*4 = 136314880
    // total ~145.9 MB

    pack_kernel<<<256, 256, 0, stream>>>(
        W_i_s, W_ste_s, W_fre_s, W_c_s, W_o_s,
        W_i_m, W_ste_m, W_fre_m, W_c_m, W_o_m,
        U_i, U_ste, U_fre, U_c, U_o,
        b_i, b_ste, b_fre, b_c, b_o,
        Wcat, bcat, UT);

    proj_kernel<<<dim3(9, 32, 8), 256, 0, stream>>>(signal, metmast, Wcat, bcat, X);

    for (int chunk = 0; chunk < NCHUNK; ++chunk) {
        recur_kernel<<<B_, 1024, 0, stream>>>(X, UT, h_g, Sre_g, Sim_g,
                                              U_a, b_a, W_p, b_p, fc_w, fc_b,
                                              out, chunk * TC);
    }
}

// Round 5
// 2539.292 us; speedup vs baseline: 4.2849x; 4.2849x over previous
//
#include <hip/hip_runtime.h>
#include <cstdint>
#include <cstddef>

#define B_    256
#define T_    128
#define SIG_  64
#define MET_  32
#define H_    256
#define F_    16
#define NCOL  1040   // [i:0..255 | ste:256..511 | c:512..767 | o:768..1023 | fre:1024..1039]
#define TC    16
#define NCHUNK (T_/TC)

__device__ __forceinline__ float hsig(float x) {
    return fminf(fmaxf(x * (1.0f/6.0f) + 0.5f, 0.0f), 1.0f);
}

__device__ __forceinline__ unsigned short f2bf(float f) {
    unsigned int u = __float_as_uint(f);
    unsigned int r = (u + 0x7fffu + ((u >> 16) & 1u)) >> 16;
    return (unsigned short)r;
}

__device__ __forceinline__ float ntload_f(const float* p) {
    return __builtin_nontemporal_load(p);
}

// column order: i(256) | ste(256) | c(256) | o(256) | fre(16)
__device__ __forceinline__ void colmap(int n, int& sec, int& idx) {
    if (n < 256)       { sec = 0; idx = n; }
    else if (n < 512)  { sec = 1; idx = n - 256; }
    else if (n < 768)  { sec = 2; idx = n - 512; }
    else if (n < 1024) { sec = 3; idx = n - 768; }
    else               { sec = 4; idx = n - 1024; }
}

// ---------------------------------------------------------------------------
// Pack weights: Wcat[96][1040] f32, bcat[1040] f32,
// U2: bf16, layout [k4][col][4] — element (k,col) at ((k>>2)*NCOL+col)*4+(k&3).
// A wave reading (k4, col0+lane) loads 8 B/lane, 512 B contiguous → coalesced.
// ---------------------------------------------------------------------------
__global__ __launch_bounds__(256) void pack_kernel(
    const float* __restrict__ Wis, const float* __restrict__ Wstes, const float* __restrict__ Wfres,
    const float* __restrict__ Wcs, const float* __restrict__ Wos,
    const float* __restrict__ Wim, const float* __restrict__ Wstem, const float* __restrict__ Wfrem,
    const float* __restrict__ Wcm, const float* __restrict__ Wom,
    const float* __restrict__ Ui, const float* __restrict__ Uste, const float* __restrict__ Ufre,
    const float* __restrict__ Uc, const float* __restrict__ Uo,
    const float* __restrict__ bi, const float* __restrict__ bste, const float* __restrict__ bfre,
    const float* __restrict__ bc, const float* __restrict__ bo,
    float* __restrict__ Wcat, float* __restrict__ bcat, unsigned short* __restrict__ U2)
{
    int gtid = blockIdx.x * blockDim.x + threadIdx.x;
    int stride = gridDim.x * blockDim.x;
    const float* Wsig[5] = {Wis, Wstes, Wcs, Wos, Wfres};
    const float* Wmet[5] = {Wim, Wstem, Wcm, Wom, Wfrem};
    const float* Us[5]   = {Ui, Uste, Uc, Uo, Ufre};
    const float* bs[5]   = {bi, bste, bc, bo, bfre};

    for (int i = gtid; i < 96*NCOL; i += stride) {
        int k = i / NCOL, n = i - k*NCOL;
        int sec, idx; colmap(n, sec, idx);
        int secN = (sec == 4) ? F_ : H_;
        float v = (k < 64) ? Wsig[sec][k*secN + idx] : Wmet[sec][(k-64)*secN + idx];
        Wcat[k*NCOL + n] = v;
    }
    for (int n = gtid; n < NCOL; n += stride) {
        int sec, idx; colmap(n, sec, idx);
        bcat[n] = bs[sec][idx];
    }
    for (int i = gtid; i < NCOL*H_; i += stride) {
        int col = i >> 8, k = i & 255;
        int sec, idx; colmap(col, sec, idx);
        int secN = (sec == 4) ? F_ : H_;
        U2[(((k >> 2) * NCOL) + col) * 4 + (k & 3)] = f2bf(Us[sec][k*secN + idx]);
    }
}

// ---------------------------------------------------------------------------
// Phase 1: input projection GEMM for ALL time steps.
// ---------------------------------------------------------------------------
__global__ __launch_bounds__(256) void proj_kernel(
    const float* __restrict__ sig, const float* __restrict__ met,
    const float* __restrict__ Wcat, const float* __restrict__ bcat,
    float* __restrict__ X)
{
    __shared__ float A_s[32][128];
    __shared__ float W_s[32][128];
    int tid = threadIdx.x;
    int c0b = blockIdx.x * 128;
    int m0  = blockIdx.y * 128;
    int t0  = blockIdx.z * 16;
    int r0  = (tid >> 4) * 8;
    int c0t = (tid & 15) * 8;

    float acc[8][8];
    #pragma unroll
    for (int i = 0; i < 8; ++i)
        #pragma unroll
        for (int j = 0; j < 8; ++j) acc[i][j] = 0.0f;

    for (int k0 = 0; k0 < 96; k0 += 32) {
        for (int idx = tid; idx < 32*128; idx += 256) {
            int ml = idx & 127, kk = idx >> 7;
            int m = m0 + ml;
            int b = m >> 4, tl = m & 15;
            int g = b * T_ + t0 + tl;
            int k = k0 + kk;
            float v = (k < 64) ? sig[g*SIG_ + k] : met[g*MET_ + (k - 64)];
            A_s[kk][ml] = v;
        }
        for (int idx = tid; idx < 32*128; idx += 256) {
            int c = idx & 127, kk = idx >> 7;
            int n = c0b + c;
            W_s[kk][c] = (n < NCOL) ? Wcat[(k0+kk)*NCOL + n] : 0.0f;
        }
        __syncthreads();
        #pragma unroll
        for (int kk = 0; kk < 32; ++kk) {
            float4 a0 = *(const float4*)&A_s[kk][r0];
            float4 a1 = *(const float4*)&A_s[kk][r0+4];
            float4 w0 = *(const float4*)&W_s[kk][c0t];
            float4 w1 = *(const float4*)&W_s[kk][c0t+4];
            float av[8] = {a0.x,a0.y,a0.z,a0.w,a1.x,a1.y,a1.z,a1.w};
            float wv[8] = {w0.x,w0.y,w0.z,w0.w,w1.x,w1.y,w1.z,w1.w};
            #pragma unroll
            for (int i = 0; i < 8; ++i)
                #pragma unroll
                for (int j = 0; j < 8; ++j)
                    acc[i][j] = fmaf(av[i], wv[j], acc[i][j]);
        }
        __syncthreads();
    }
    #pragma unroll
    for (int i = 0; i < 8; ++i) {
        int m = m0 + r0 + i;
        int bb = m >> 4, tl = m & 15;
        size_t row = (size_t)bb * T_ + t0 + tl;
        #pragma unroll
        for (int j = 0; j < 8; ++j) {
            int n = c0b + c0t + j;
            if (n < NCOL) X[row*NCOL + n] = acc[i][j] + bcat[n];
        }
    }
}

// ---------------------------------------------------------------------------
// Phase 2: recurrence, chunk of TC steps. 512 threads (8 waves), 2 batches
// per block (grid = 128). __launch_bounds__(512,2) => VGPR cap 256 => NO
// scratch spills (the R2-R4 killer: LB(1024) capped VGPR at 64, spilling
// Sre/Sim to scratch; 340 MB/dispatch of scratch writes thrashed UT out of
// L2). Dot phase: thread owns cols {tid, tid+512} for BOTH batches (U load
// shared); tid<32 also compute the 16 fre cols per batch. Update phase:
// thread (b=tid>>8, j=tid&255) owns all 16 f of one (batch,row).
// ---------------------------------------------------------------------------
__device__ __forceinline__ void unp4(uint2 u, float4& f) {
    f.x = __uint_as_float(u.x << 16);
    f.y = __uint_as_float(u.x & 0xffff0000u);
    f.z = __uint_as_float(u.y << 16);
    f.w = __uint_as_float(u.y & 0xffff0000u);
}
__device__ __forceinline__ float fma4(float4 u, float4 h, float acc) {
    acc = fmaf(u.x, h.x, acc);
    acc = fmaf(u.y, h.y, acc);
    acc = fmaf(u.z, h.z, acc);
    acc = fmaf(u.w, h.w, acc);
    return acc;
}

__global__ __launch_bounds__(512, 2) void recur_kernel(
    const float* __restrict__ X, const uint2* __restrict__ U2,
    float* __restrict__ h_g, float* __restrict__ Sre_g, float* __restrict__ Sim_g,
    const float* __restrict__ U_a, const float* __restrict__ b_a,
    const float* __restrict__ W_p, const float* __restrict__ b_p,
    const float* __restrict__ fc_w, const float* __restrict__ fc_b,
    float* __restrict__ out, int t0)
{
    __shared__ float h_s[2][H_];
    __shared__ float pre_s[2][NCOL];
    __shared__ float cs_s[16], sn_s[16], ua_s[16];

    int tid  = threadIdx.x;
    int b0   = blockIdx.x * 2;
    int bloc = tid >> 8;          // update-phase batch (0/1)
    int j    = tid & 255;         // update-phase h row
    int col_a = tid;
    int col_b = tid + 512;
    bool isfre = (tid < 32);
    int fb = tid >> 4;            // fre batch (when isfre)
    int ff = tid & 15;            // fre index (when isfre)

    float Sre[16], Sim[16];
    if (t0 == 0) {
        h_s[bloc][j] = 0.0f;
        #pragma unroll
        for (int f = 0; f < 16; ++f) { Sre[f] = 0.0f; Sim[f] = 0.0f; }
    } else {
        h_s[bloc][j] = h_g[(b0 + bloc)*H_ + j];
        const float4* pr = (const float4*)(Sre_g + ((size_t)(b0 + bloc)*H_ + j)*16);
        const float4* pi = (const float4*)(Sim_g + ((size_t)(b0 + bloc)*H_ + j)*16);
        #pragma unroll
        for (int q = 0; q < 4; ++q) {
            float4 r = pr[q], im = pi[q];
            Sre[q*4+0]=r.x; Sre[q*4+1]=r.y; Sre[q*4+2]=r.z; Sre[q*4+3]=r.w;
            Sim[q*4+0]=im.x; Sim[q*4+1]=im.y; Sim[q*4+2]=im.z; Sim[q*4+3]=im.w;
        }
    }
    if (tid < 16) {
        float ang = (float)tid * 0.39269908169872414f; // 2*pi/16
        cs_s[tid] = cosf(ang);
        sn_s[tid] = sinf(ang);
        ua_s[tid] = U_a[tid];
    }
    float ba_j = b_a[j];
    __syncthreads();

    const float* x0base = X + ((size_t)b0       * T_ + t0) * NCOL;
    const float* x1base = X + ((size_t)(b0 + 1) * T_ + t0) * NCOL;

    float hnew = h_s[bloc][j];

    for (int tl = 0; tl < TC; ++tl) {
        const float* x0 = x0base + (size_t)tl * NCOL;
        const float* x1 = x1base + (size_t)tl * NCOL;

        // ---- dot phase ----
        float aa0 = ntload_f(&x0[col_a]);
        float aa1 = ntload_f(&x1[col_a]);
        float ab0 = ntload_f(&x0[col_b]);
        float ab1 = ntload_f(&x1[col_b]);
        float af  = 0.0f;
        if (isfre) af = ntload_f(&((fb ? x1 : x0)[1024 + ff]));

        #pragma unroll 4
        for (int kk = 0; kk < 64; ++kk) {
            float4 h0 = *(const float4*)&h_s[0][kk*4];
            float4 h1 = *(const float4*)&h_s[1][kk*4];
            uint2 ua = U2[kk*NCOL + col_a];
            uint2 ub = U2[kk*NCOL + col_b];
            float4 fua, fub;
            unp4(ua, fua);
            unp4(ub, fub);
            aa0 = fma4(fua, h0, aa0);
            aa1 = fma4(fua, h1, aa1);
            ab0 = fma4(fub, h0, ab0);
            ab1 = fma4(fub, h1, ab1);
            if (isfre) {
                uint2 uf = U2[kk*NCOL + 1024 + ff];
                float4 fuf; unp4(uf, fuf);
                float4 hf = fb ? h1 : h0;
                af = fma4(fuf, hf, af);
            }
        }
        pre_s[0][col_a] = aa0;
        pre_s[1][col_a] = aa1;
        pre_s[0][col_b] = ab0;
        pre_s[1][col_b] = ab1;
        if (isfre) pre_s[fb][1024 + ff] = af;
        __syncthreads();   // A: pre_s ready; h_s reads done

        // ---- update phase: thread (bloc, j) ----
        float xi   = pre_s[bloc][j];
        float xste = pre_s[bloc][256 + j];
        float xc   = pre_s[bloc][512 + j];
        float xo   = pre_s[bloc][768 + j];
        float gi   = hsig(xi);
        float gste = hsig(xste);
        float go   = hsig(xo);
        float cc   = gi * tanhf(xc);

        int tt1 = (t0 + tl + 1) & 15;
        float Aa = 0.0f;
        #pragma unroll
        for (int f = 0; f < 16; ++f) {
            float fre = hsig(pre_s[bloc][1024 + f]);
            int idx = (tt1 * f) & 15;
            float dec = gste * fre;
            float sre = fmaf(dec, Sre[f], cc * cs_s[idx]);
            float sim = fmaf(dec, Sim[f], cc * sn_s[idx]);
            Sre[f] = sre; Sim[f] = sim;
            Aa = fmaf(fmaf(sre, sre, sim*sim), ua_s[f], Aa);
        }
        hnew = go * tanhf(Aa + ba_j);
        h_s[bloc][j] = hnew;
        __syncthreads();   // B: h_s ready; pre_s reads done
    }

    // ---- spill state for next chunk ----
    h_g[(b0 + bloc)*H_ + j] = hnew;
    float4* pr = (float4*)(Sre_g + ((size_t)(b0 + bloc)*H_ + j)*16);
    float4* pi = (float4*)(Sim_g + ((size_t)(b0 + bloc)*H_ + j)*16);
    #pragma unroll
    for (int q = 0; q < 4; ++q) {
        float4 r, im;
        r.x = Sre[q*4+0]; r.y = Sre[q*4+1]; r.z = Sre[q*4+2]; r.w = Sre[q*4+3];
        im.x = Sim[q*4+0]; im.y = Sim[q*4+1]; im.z = Sim[q*4+2]; im.w = Sim[q*4+3];
        pr[q] = r; pi[q] = im;
    }

    if (t0 + TC == T_) {
        // ---- head: out[b] = (sum_j h[j]*W_p[j] + b_p)*fc_w + fc_b ----
        pre_s[bloc][j] = hnew * W_p[j];
        __syncthreads();
        for (int s = 128; s > 0; s >>= 1) {
            if (j < s) pre_s[bloc][j] += pre_s[bloc][j + s];
            __syncthreads();
        }
        if (j == 0) out[b0 + bloc] = (pre_s[bloc][0] + b_p[0]) * fc_w[0] + fc_b[0];
    }
}

// ---------------------------------------------------------------------------
extern "C" void kernel_launch(void* const* d_in, const int* in_sizes, int n_in,
                              void* d_out, int out_size, void* d_ws, size_t ws_size,
                              hipStream_t stream) {
    const float* signal = (const float*)d_in[0];
    const float* metmast = (const float*)d_in[1];
    const float* W_i_s   = (const float*)d_in[2];
    const float* W_ste_s = (const float*)d_in[3];
    const float* W_fre_s = (const float*)d_in[4];
    const float* W_c_s   = (const float*)d_in[5];
    const float* W_o_s   = (const float*)d_in[6];
    const float* W_i_m   = (const float*)d_in[7];
    const float* W_ste_m = (const float*)d_in[8];
    const float* W_fre_m = (const float*)d_in[9];
    const float* W_c_m   = (const float*)d_in[10];
    const float* W_o_m   = (const float*)d_in[11];
    const float* U_i   = (const float*)d_in[12];
    const float* b_i   = (const float*)d_in[13];
    const float* U_ste = (const float*)d_in[14];
    const float* b_ste = (const float*)d_in[15];
    const float* U_fre = (const float*)d_in[16];
    const float* b_fre = (const float*)d_in[17];
    const float* U_c   = (const float*)d_in[18];
    const float* b_c   = (const float*)d_in[19];
    const float* U_o   = (const float*)d_in[20];
    const float* b_o   = (const float*)d_in[21];
    const float* U_a   = (const float*)d_in[22];
    const float* b_a   = (const float*)d_in[23];
    const float* W_p   = (const float*)d_in[24];
    const float* b_p   = (const float*)d_in[25];
    const float* fc_w  = (const float*)d_in[26];
    const float* fc_b  = (const float*)d_in[27];
    float* out = (float*)d_out;

    char* ws = (char*)d_ws;
    float*          Wcat = (float*)(ws + 0);                 //  96*1040*4 = 399360
    float*          bcat = (float*)(ws + 399360);            //  1040*4    = 4160
    unsigned short* U2   = (unsigned short*)(ws + 403520);   //  64*1040*4*2 = 532480
    float*          h_g  = (float*)(ws + 936000);            //  256*256*4 = 262144
    float*          Sre_g= (float*)(ws + 1198144);           //  4194304
    float*          Sim_g= (float*)(ws + 5392448);           //  4194304
    float*          X    = (float*)(ws + 9586752);           //  256*128*1040*4 = 136314880
    // total ~145.9 MB

    pack_kernel<<<256, 256, 0, stream>>>(
        W_i_s, W_ste_s, W_fre_s, W_c_s, W_o_s,
        W_i_m, W_ste_m, W_fre_m, W_c_m, W_o_m,
        U_i, U_ste, U_fre, U_c, U_o,
        b_i, b_ste, b_fre, b_c, b_o,
        Wcat, bcat, U2);

    proj_kernel<<<dim3(9, 32, 8), 256, 0, stream>>>(signal, metmast, Wcat, bcat, X);

    for (int chunk = 0; chunk < NCHUNK; ++chunk) {
        recur_kernel<<<B_/2, 512, 0, stream>>>(X, (const uint2*)U2, h_g, Sre_g, Sim_g,
                                               U_a, b_a, W_p, b_p, fc_w, fc_b,
                                               out, chunk * TC);
    }
}

// Round 6
// 1173.902 us; speedup vs baseline: 9.2688x; 2.1631x over previous
//
#include <hip/hip_runtime.h>
#include <cstdint>
#include <cstddef>

#define B_    256
#define T_    128
#define SIG_  64
#define MET_  32
#define H_    256
#define F_    16
#define NCOL  1040   // X cols: [i:0..255 | ste:256..511 | c:512..767 | o:768..1023 | fre:1024..1039]

__device__ __forceinline__ float hsig(float x) {
    return fminf(fmaxf(x * (1.0f/6.0f) + 0.5f, 0.0f), 1.0f);
}

__device__ __forceinline__ unsigned short f2bf(float f) {
    unsigned int u = __float_as_uint(f);
    unsigned int r = (u + 0x7fffu + ((u >> 16) & 1u)) >> 16;
    return (unsigned short)r;
}

__device__ __forceinline__ float ntload_f(const float* p) {
    return __builtin_nontemporal_load(p);
}
__device__ __forceinline__ float4 ntload_f4(const float* p) {
    float4 v;
    v.x = __builtin_nontemporal_load(p + 0);
    v.y = __builtin_nontemporal_load(p + 1);
    v.z = __builtin_nontemporal_load(p + 2);
    v.w = __builtin_nontemporal_load(p + 3);
    return v;
}

// main col order: i(256) | ste(256) | c(256) | o(256); fre(16) separate
__device__ __forceinline__ void colmap4(int n, int& sec, int& idx) {
    sec = n >> 8; idx = n & 255;
}

// ---------------------------------------------------------------------------
// Pack: Wcat[96][1040] f32, bcat[1040] f32,
// U8: bf16 main cols, layout [k8][col][8] — uint4 index k8*1024+col holds
//     U[k8*8 .. k8*8+7][col]. Wave reads (kk, col=tid): 16 B/lane, 1 KB
//     contiguous per wave -> perfectly coalesced, lines fully consumed.
// UF: bf16 fre cols, [col][k] contiguous (col 0..15).
// ---------------------------------------------------------------------------
__global__ __launch_bounds__(256) void pack_kernel(
    const float* __restrict__ Wis, const float* __restrict__ Wstes, const float* __restrict__ Wfres,
    const float* __restrict__ Wcs, const float* __restrict__ Wos,
    const float* __restrict__ Wim, const float* __restrict__ Wstem, const float* __restrict__ Wfrem,
    const float* __restrict__ Wcm, const float* __restrict__ Wom,
    const float* __restrict__ Ui, const float* __restrict__ Uste, const float* __restrict__ Ufre,
    const float* __restrict__ Uc, const float* __restrict__ Uo,
    const float* __restrict__ bi, const float* __restrict__ bste, const float* __restrict__ bfre,
    const float* __restrict__ bc, const float* __restrict__ bo,
    float* __restrict__ Wcat, float* __restrict__ bcat,
    unsigned short* __restrict__ U8, unsigned short* __restrict__ UF)
{
    int gtid = blockIdx.x * blockDim.x + threadIdx.x;
    int stride = gridDim.x * blockDim.x;
    const float* Wsig[5] = {Wis, Wstes, Wcs, Wos, Wfres};
    const float* Wmet[5] = {Wim, Wstem, Wcm, Wom, Wfrem};
    const float* Us[4]   = {Ui, Uste, Uc, Uo};
    const float* bs[5]   = {bi, bste, bc, bo, bfre};

    for (int i = gtid; i < 96*NCOL; i += stride) {
        int k = i / NCOL, n = i - k*NCOL;
        int sec, idx, secN;
        if (n < 1024) { sec = n >> 8; idx = n & 255; secN = H_; }
        else          { sec = 4; idx = n - 1024; secN = F_; }
        float v = (k < 64) ? Wsig[sec][k*secN + idx] : Wmet[sec][(k-64)*secN + idx];
        Wcat[k*NCOL + n] = v;
    }
    for (int n = gtid; n < NCOL; n += stride) {
        int sec, idx;
        if (n < 1024) { sec = n >> 8; idx = n & 255; }
        else          { sec = 4; idx = n - 1024; }
        bcat[n] = bs[sec][idx];
    }
    // main 1024 cols
    for (int i = gtid; i < 1024*H_; i += stride) {
        int col = i >> 8, k = i & 255;
        int sec = col >> 8, idx = col & 255;
        float v = Us[sec][k*H_ + idx];
        U8[(((k >> 3) * 1024) + col) * 8 + (k & 7)] = f2bf(v);
    }
    // fre 16 cols
    for (int i = gtid; i < 16*H_; i += stride) {
        int col = i >> 8, k = i & 255;
        UF[col*H_ + k] = f2bf(Ufre[k*F_ + col]);
    }
}

// ---------------------------------------------------------------------------
// Phase 1: input projection GEMM for ALL time steps.
// ---------------------------------------------------------------------------
__global__ __launch_bounds__(256) void proj_kernel(
    const float* __restrict__ sig, const float* __restrict__ met,
    const float* __restrict__ Wcat, const float* __restrict__ bcat,
    float* __restrict__ X)
{
    __shared__ float A_s[32][128];
    __shared__ float W_s[32][128];
    int tid = threadIdx.x;
    int c0b = blockIdx.x * 128;
    int m0  = blockIdx.y * 128;
    int t0  = blockIdx.z * 16;
    int r0  = (tid >> 4) * 8;
    int c0t = (tid & 15) * 8;

    float acc[8][8];
    #pragma unroll
    for (int i = 0; i < 8; ++i)
        #pragma unroll
        for (int j = 0; j < 8; ++j) acc[i][j] = 0.0f;

    for (int k0 = 0; k0 < 96; k0 += 32) {
        for (int idx = tid; idx < 32*128; idx += 256) {
            int ml = idx & 127, kk = idx >> 7;
            int m = m0 + ml;
            int b = m >> 4, tl = m & 15;
            int g = b * T_ + t0 + tl;
            int k = k0 + kk;
            float v = (k < 64) ? sig[g*SIG_ + k] : met[g*MET_ + (k - 64)];
            A_s[kk][ml] = v;
        }
        for (int idx = tid; idx < 32*128; idx += 256) {
            int c = idx & 127, kk = idx >> 7;
            int n = c0b + c;
            W_s[kk][c] = (n < NCOL) ? Wcat[(k0+kk)*NCOL + n] : 0.0f;
        }
        __syncthreads();
        #pragma unroll
        for (int kk = 0; kk < 32; ++kk) {
            float4 a0 = *(const float4*)&A_s[kk][r0];
            float4 a1 = *(const float4*)&A_s[kk][r0+4];
            float4 w0 = *(const float4*)&W_s[kk][c0t];
            float4 w1 = *(const float4*)&W_s[kk][c0t+4];
            float av[8] = {a0.x,a0.y,a0.z,a0.w,a1.x,a1.y,a1.z,a1.w};
            float wv[8] = {w0.x,w0.y,w0.z,w0.w,w1.x,w1.y,w1.z,w1.w};
            #pragma unroll
            for (int i = 0; i < 8; ++i)
                #pragma unroll
                for (int j = 0; j < 8; ++j)
                    acc[i][j] = fmaf(av[i], wv[j], acc[i][j]);
        }
        __syncthreads();
    }
    #pragma unroll
    for (int i = 0; i < 8; ++i) {
        int m = m0 + r0 + i;
        int bb = m >> 4, tl = m & 15;
        size_t row = (size_t)bb * T_ + t0 + tl;
        #pragma unroll
        for (int j = 0; j < 8; ++j) {
            int n = c0b + c0t + j;
            if (n < NCOL) X[row*NCOL + n] = acc[i][j] + bcat[n];
        }
    }
}

// ---------------------------------------------------------------------------
// Phase 2: full recurrence, SINGLE monolithic launch. grid=256 (1 batch per
// block), 1024 threads (16 waves/CU = 4/SIMD for latency hiding).
// __launch_bounds__(1024,4) => 128-VGPR cap => NO scratch spills (R2-R4's
// killer was LB-induced 64-VGPR spilling; R5 proved no-spill => UT stays
// L2-resident, FETCH 14.7 MB/dispatch).
// Dot phase: thread owns main col tid; U8 wave-loads are 1 KB contiguous.
// fre cols: wave w owns fre col w, lanes {15,31,47,63} compute 64-k quarter
// dots, combined via qp[] in LDS. Update: 4 threads per row (Sre[4]/Sim[4]
// each), Aa combined via shfl_xor — proven R2 numerics (absmax 9.5e-7).
// ---------------------------------------------------------------------------
__device__ __forceinline__ float dot8(uint4 u, float4 ha, float4 hb, float acc) {
    acc = fmaf(__uint_as_float(u.x << 16),          ha.x, acc);
    acc = fmaf(__uint_as_float(u.x & 0xffff0000u),  ha.y, acc);
    acc = fmaf(__uint_as_float(u.y << 16),          ha.z, acc);
    acc = fmaf(__uint_as_float(u.y & 0xffff0000u),  ha.w, acc);
    acc = fmaf(__uint_as_float(u.z << 16),          hb.x, acc);
    acc = fmaf(__uint_as_float(u.z & 0xffff0000u),  hb.y, acc);
    acc = fmaf(__uint_as_float(u.w << 16),          hb.z, acc);
    acc = fmaf(__uint_as_float(u.w & 0xffff0000u),  hb.w, acc);
    return acc;
}

__global__ __launch_bounds__(1024, 4) void recur_kernel(
    const float* __restrict__ X, const uint4* __restrict__ U8,
    const uint4* __restrict__ UF,
    const float* __restrict__ U_a, const float* __restrict__ b_a,
    const float* __restrict__ W_p, const float* __restrict__ b_p,
    const float* __restrict__ fc_w, const float* __restrict__ fc_b,
    float* __restrict__ out)
{
    __shared__ float h_s[H_];
    __shared__ float pre_s[1024];
    __shared__ float qp[64];          // fre quarter partials: qp[f*4+q]
    __shared__ float cs_s[16], sn_s[16];

    int tid  = threadIdx.x;
    int b    = blockIdx.x;
    int lane = tid & 63;
    int wid  = tid >> 6;
    bool isfre = ((lane & 15) == 15);
    int fq = lane >> 4;               // quarter 0..3 (when isfre)

    // update-phase ownership: j = tid>>2 (h row), f0 = (tid&3)*4 (f range)
    int j  = tid >> 2;
    int f0 = (tid & 3) * 4;

    if (tid < H_) h_s[tid] = 0.0f;
    if (tid < 16) {
        float ang = (float)tid * 0.39269908169872414f; // 2*pi/16
        cs_s[tid] = cosf(ang);
        sn_s[tid] = sinf(ang);
    }
    float Sre[4], Sim[4];
    #pragma unroll
    for (int r = 0; r < 4; ++r) { Sre[r] = 0.0f; Sim[r] = 0.0f; }

    float ba_j = b_a[j];
    float4 ua4 = ((const float4*)U_a)[tid & 3];
    const uint4* Uf = UF + (wid * 32 + fq * 8);   // quarter fq of fre col wid
    const float* Xb = X + (size_t)b * T_ * NCOL;

    float hnew = 0.0f;
    __syncthreads();

    for (int t = 0; t < T_; ++t) {
        const float* xrow = Xb + (size_t)t * NCOL;

        // ---- dot phase: pre[col=tid] = x + U[:,col] . h ----
        float acc = ntload_f(&xrow[tid]);
        #pragma unroll 8
        for (int kk = 0; kk < 32; ++kk) {
            uint4 u = U8[kk * 1024 + tid];
            float4 ha = *(const float4*)&h_s[kk*8];
            float4 hb = *(const float4*)&h_s[kk*8 + 4];
            acc = dot8(u, ha, hb, acc);
        }
        float fa = 0.0f;
        if (isfre) {
            #pragma unroll
            for (int q = 0; q < 8; ++q) {
                uint4 u = Uf[q];
                float4 ha = *(const float4*)&h_s[fq*64 + q*8];
                float4 hb = *(const float4*)&h_s[fq*64 + q*8 + 4];
                fa = dot8(u, ha, hb, fa);
            }
        }
        pre_s[tid] = acc;
        if (isfre) qp[wid*4 + fq] = fa;
        __syncthreads();   // A: pre_s + qp ready; h_s reads done

        // ---- update phase ----
        float xi   = pre_s[j];
        float xste = pre_s[256 + j];
        float xc   = pre_s[512 + j];
        float xo   = pre_s[768 + j];
        float gi   = hsig(xi);
        float gste = hsig(xste);
        float go   = hsig(xo);
        float cc   = gi * tanhf(xc);

        float4 xfre = ntload_f4(&xrow[1024 + f0]);
        float4 q0 = *(const float4*)&qp[(f0+0)*4];
        float4 q1 = *(const float4*)&qp[(f0+1)*4];
        float4 q2 = *(const float4*)&qp[(f0+2)*4];
        float4 q3 = *(const float4*)&qp[(f0+3)*4];
        float fre[4];
        fre[0] = hsig(xfre.x + q0.x + q0.y + q0.z + q0.w);
        fre[1] = hsig(xfre.y + q1.x + q1.y + q1.z + q1.w);
        fre[2] = hsig(xfre.z + q2.x + q2.y + q2.z + q2.w);
        fre[3] = hsig(xfre.w + q3.x + q3.y + q3.z + q3.w);

        int tt1 = (t + 1) & 15;
        float Aa = 0.0f;
        #pragma unroll
        for (int r = 0; r < 4; ++r) {
            int idx = (tt1 * (f0 + r)) & 15;
            float dec = gste * fre[r];
            float sre = fmaf(dec, Sre[r], cc * cs_s[idx]);
            float sim = fmaf(dec, Sim[r], cc * sn_s[idx]);
            Sre[r] = sre; Sim[r] = sim;
            Aa = fmaf(fmaf(sre, sre, sim*sim), ((const float*)&ua4)[r], Aa);
        }
        Aa += __shfl_xor(Aa, 1);
        Aa += __shfl_xor(Aa, 2);
        if ((tid & 3) == 0) {
            float a = tanhf(Aa + ba_j);
            hnew = go * a;
            h_s[j] = hnew;
        }
        __syncthreads();   // B: h_s ready; pre_s/qp reads done
    }

    // ---- head: out[b] = (sum_j h[j]*W_p[j] + b_p)*fc_w + fc_b ----
    if ((tid & 3) == 0) pre_s[j] = hnew * W_p[j];
    __syncthreads();
    for (int s = 128; s > 0; s >>= 1) {
        if (tid < s) pre_s[tid] += pre_s[tid + s];
        __syncthreads();
    }
    if (tid == 0) out[b] = (pre_s[0] + b_p[0]) * fc_w[0] + fc_b[0];
}

// ---------------------------------------------------------------------------
extern "C" void kernel_launch(void* const* d_in, const int* in_sizes, int n_in,
                              void* d_out, int out_size, void* d_ws, size_t ws_size,
                              hipStream_t stream) {
    const float* signal = (const float*)d_in[0];
    const float* metmast = (const float*)d_in[1];
    const float* W_i_s   = (const float*)d_in[2];
    const float* W_ste_s = (const float*)d_in[3];
    const float* W_fre_s = (const float*)d_in[4];
    const float* W_c_s   = (const float*)d_in[5];
    const float* W_o_s   = (const float*)d_in[6];
    const float* W_i_m   = (const float*)d_in[7];
    const float* W_ste_m = (const float*)d_in[8];
    const float* W_fre_m = (const float*)d_in[9];
    const float* W_c_m   = (const float*)d_in[10];
    const float* W_o_m   = (const float*)d_in[11];
    const float* U_i   = (const float*)d_in[12];
    const float* b_i   = (const float*)d_in[13];
    const float* U_ste = (const float*)d_in[14];
    const float* b_ste = (const float*)d_in[15];
    const float* U_fre = (const float*)d_in[16];
    const float* b_fre = (const float*)d_in[17];
    const float* U_c   = (const float*)d_in[18];
    const float* b_c   = (const float*)d_in[19];
    const float* U_o   = (const float*)d_in[20];
    const float* b_o   = (const float*)d_in[21];
    const float* U_a   = (const float*)d_in[22];
    const float* b_a   = (const float*)d_in[23];
    const float* W_p   = (const float*)d_in[24];
    const float* b_p   = (const float*)d_in[25];
    const float* fc_w  = (const float*)d_in[26];
    const float* fc_b  = (const float*)d_in[27];
    float* out = (float*)d_out;

    char* ws = (char*)d_ws;
    float*          Wcat = (float*)(ws + 0);                 //  96*1040*4 = 399360
    float*          bcat = (float*)(ws + 399360);            //  1040*4    = 4160
    unsigned short* U8   = (unsigned short*)(ws + 403520);   //  1024*256*2 = 524288
    unsigned short* UF   = (unsigned short*)(ws + 927808);   //  16*256*2   = 8192
    float*          X    = (float*)(ws + 936000);            //  256*128*1040*4 = 136314880
    // total ~137.3 MB

    pack_kernel<<<256, 256, 0, stream>>>(
        W_i_s, W_ste_s, W_fre_s, W_c_s, W_o_s,
        W_i_m, W_ste_m, W_fre_m, W_c_m, W_o_m,
        U_i, U_ste, U_fre, U_c, U_o,
        b_i, b_ste, b_fre, b_c, b_o,
        Wcat, bcat, U8, UF);

    proj_kernel<<<dim3(9, 32, 8), 256, 0, stream>>>(signal, metmast, Wcat, bcat, X);

    recur_kernel<<<B_, 1024, 0, stream>>>(X, (const uint4*)U8, (const uint4*)UF,
                                          U_a, b_a, W_p, b_p, fc_w, fc_b, out);
}

// Round 7
// 1096.843 us; speedup vs baseline: 9.9200x; 1.0703x over previous
//
#include <hip/hip_runtime.h>
#include <hip/hip_fp16.h>
#include <cstdint>
#include <cstddef>

#define B_    256
#define T_    128
#define SIG_  64
#define MET_  32
#define H_    256
#define F_    16
#define NCOL  1040   // X cols: [i:0..255 | ste:256..511 | c:512..767 | o:768..1023 | fre:1024..1039]

__device__ __forceinline__ float hsig(float x) {
    return fminf(fmaxf(x * (1.0f/6.0f) + 0.5f, 0.0f), 1.0f);
}

__device__ __forceinline__ unsigned short f2h(float f) {
    __half h = __float2half(f);
    return *(unsigned short*)&h;
}

__device__ __forceinline__ float ntload_f(const float* p) {
    return __builtin_nontemporal_load(p);
}
__device__ __forceinline__ float4 ntload_f4(const float* p) {
    float4 v;
    v.x = __builtin_nontemporal_load(p + 0);
    v.y = __builtin_nontemporal_load(p + 1);
    v.z = __builtin_nontemporal_load(p + 2);
    v.w = __builtin_nontemporal_load(p + 3);
    return v;
}

typedef _Float16 half2v __attribute__((ext_vector_type(2)));

// v_dot2_f32_f16: 2 fp16 MACs, f32 accumulate — one VOP3P instr (vs 2 fma +
// 2 unpack for bf16). This is the R7 VALU-issue fix (R6: VALUBusy 83%).
__device__ __forceinline__ float dot2(unsigned int u, unsigned int h, float acc) {
#if __has_builtin(__builtin_amdgcn_fdot2)
    return __builtin_amdgcn_fdot2(__builtin_bit_cast(half2v, u),
                                  __builtin_bit_cast(half2v, h), acc, false);
#else
    __half2 uu = *(__half2*)&u, hh = *(__half2*)&h;
    float2 uf = __half22float2(uu), hf = __half22float2(hh);
    return fmaf(uf.x, hf.x, fmaf(uf.y, hf.y, acc));
#endif
}

// ---------------------------------------------------------------------------
// Pack: Wcat[96][1040] f32, bcat[1040] f32,
// U8: fp16 main cols, layout [k8][col][8] — uint4 index k8*1024+col holds
//     U[k8*8 .. k8*8+7][col]. Wave reads (kk, col=tid): 16 B/lane, 1 KB
//     contiguous per wave -> perfectly coalesced.
// UF: fp16 fre cols, [col][k] contiguous (col 0..15).
// ---------------------------------------------------------------------------
__global__ __launch_bounds__(256) void pack_kernel(
    const float* __restrict__ Wis, const float* __restrict__ Wstes, const float* __restrict__ Wfres,
    const float* __restrict__ Wcs, const float* __restrict__ Wos,
    const float* __restrict__ Wim, const float* __restrict__ Wstem, const float* __restrict__ Wfrem,
    const float* __restrict__ Wcm, const float* __restrict__ Wom,
    const float* __restrict__ Ui, const float* __restrict__ Uste, const float* __restrict__ Ufre,
    const float* __restrict__ Uc, const float* __restrict__ Uo,
    const float* __restrict__ bi, const float* __restrict__ bste, const float* __restrict__ bfre,
    const float* __restrict__ bc, const float* __restrict__ bo,
    float* __restrict__ Wcat, float* __restrict__ bcat,
    unsigned short* __restrict__ U8, unsigned short* __restrict__ UF)
{
    int gtid = blockIdx.x * blockDim.x + threadIdx.x;
    int stride = gridDim.x * blockDim.x;
    const float* Wsig[5] = {Wis, Wstes, Wcs, Wos, Wfres};
    const float* Wmet[5] = {Wim, Wstem, Wcm, Wom, Wfrem};
    const float* Us[4]   = {Ui, Uste, Uc, Uo};
    const float* bs[5]   = {bi, bste, bc, bo, bfre};

    for (int i = gtid; i < 96*NCOL; i += stride) {
        int k = i / NCOL, n = i - k*NCOL;
        int sec, idx, secN;
        if (n < 1024) { sec = n >> 8; idx = n & 255; secN = H_; }
        else          { sec = 4; idx = n - 1024; secN = F_; }
        float v = (k < 64) ? Wsig[sec][k*secN + idx] : Wmet[sec][(k-64)*secN + idx];
        Wcat[k*NCOL + n] = v;
    }
    for (int n = gtid; n < NCOL; n += stride) {
        int sec, idx;
        if (n < 1024) { sec = n >> 8; idx = n & 255; }
        else          { sec = 4; idx = n - 1024; }
        bcat[n] = bs[sec][idx];
    }
    // main 1024 cols
    for (int i = gtid; i < 1024*H_; i += stride) {
        int col = i >> 8, k = i & 255;
        int sec = col >> 8, idx = col & 255;
        float v = Us[sec][k*H_ + idx];
        U8[(((k >> 3) * 1024) + col) * 8 + (k & 7)] = f2h(v);
    }
    // fre 16 cols
    for (int i = gtid; i < 16*H_; i += stride) {
        int col = i >> 8, k = i & 255;
        UF[col*H_ + k] = f2h(Ufre[k*F_ + col]);
    }
}

// ---------------------------------------------------------------------------
// Phase 1: input projection GEMM for ALL time steps.
// ---------------------------------------------------------------------------
__global__ __launch_bounds__(256) void proj_kernel(
    const float* __restrict__ sig, const float* __restrict__ met,
    const float* __restrict__ Wcat, const float* __restrict__ bcat,
    float* __restrict__ X)
{
    __shared__ float A_s[32][128];
    __shared__ float W_s[32][128];
    int tid = threadIdx.x;
    int c0b = blockIdx.x * 128;
    int m0  = blockIdx.y * 128;
    int t0  = blockIdx.z * 16;
    int r0  = (tid >> 4) * 8;
    int c0t = (tid & 15) * 8;

    float acc[8][8];
    #pragma unroll
    for (int i = 0; i < 8; ++i)
        #pragma unroll
        for (int j = 0; j < 8; ++j) acc[i][j] = 0.0f;

    for (int k0 = 0; k0 < 96; k0 += 32) {
        for (int idx = tid; idx < 32*128; idx += 256) {
            int ml = idx & 127, kk = idx >> 7;
            int m = m0 + ml;
            int b = m >> 4, tl = m & 15;
            int g = b * T_ + t0 + tl;
            int k = k0 + kk;
            float v = (k < 64) ? sig[g*SIG_ + k] : met[g*MET_ + (k - 64)];
            A_s[kk][ml] = v;
        }
        for (int idx = tid; idx < 32*128; idx += 256) {
            int c = idx & 127, kk = idx >> 7;
            int n = c0b + c;
            W_s[kk][c] = (n < NCOL) ? Wcat[(k0+kk)*NCOL + n] : 0.0f;
        }
        __syncthreads();
        #pragma unroll
        for (int kk = 0; kk < 32; ++kk) {
            float4 a0 = *(const float4*)&A_s[kk][r0];
            float4 a1 = *(const float4*)&A_s[kk][r0+4];
            float4 w0 = *(const float4*)&W_s[kk][c0t];
            float4 w1 = *(const float4*)&W_s[kk][c0t+4];
            float av[8] = {a0.x,a0.y,a0.z,a0.w,a1.x,a1.y,a1.z,a1.w};
            float wv[8] = {w0.x,w0.y,w0.z,w0.w,w1.x,w1.y,w1.z,w1.w};
            #pragma unroll
            for (int i = 0; i < 8; ++i)
                #pragma unroll
                for (int j = 0; j < 8; ++j)
                    acc[i][j] = fmaf(av[i], wv[j], acc[i][j]);
        }
        __syncthreads();
    }
    #pragma unroll
    for (int i = 0; i < 8; ++i) {
        int m = m0 + r0 + i;
        int bb = m >> 4, tl = m & 15;
        size_t row = (size_t)bb * T_ + t0 + tl;
        #pragma unroll
        for (int j = 0; j < 8; ++j) {
            int n = c0b + c0t + j;
            if (n < NCOL) X[row*NCOL + n] = acc[i][j] + bcat[n];
        }
    }
}

// ---------------------------------------------------------------------------
// Phase 2: full recurrence, SINGLE launch. grid=256 (1 batch/block), 1024
// threads (4 waves/SIMD). LB(1024,4): VGPR<=128; R6 measured VGPR=64 with
// WRITE_SIZE=8B => no scratch spills (the R2-R4 killer).
// R7 change: U and h in fp16, dot via v_dot2_f32_f16 — 4x fewer dot-phase
// VALU ops than bf16 shift/and+fma (R6: VALUBusy 83%, issue-bound).
// h lives in LDS as packed fp16 pairs (h_p[128] dwords); update phase is
// unchanged f32 (proven numerics).
// ---------------------------------------------------------------------------
__global__ __launch_bounds__(1024, 4) void recur_kernel(
    const float* __restrict__ X, const uint4* __restrict__ U8,
    const uint4* __restrict__ UF,
    const float* __restrict__ U_a, const float* __restrict__ b_a,
    const float* __restrict__ W_p, const float* __restrict__ b_p,
    const float* __restrict__ fc_w, const float* __restrict__ fc_b,
    float* __restrict__ out)
{
    __shared__ unsigned int h_p[H_/2];   // h as packed fp16 pairs
    __shared__ float pre_s[1024];
    __shared__ float qp[64];             // fre quarter partials: qp[f*4+q]
    __shared__ float cs_s[16], sn_s[16];

    int tid  = threadIdx.x;
    int b    = blockIdx.x;
    int lane = tid & 63;
    int wid  = tid >> 6;
    bool isfre = ((lane & 15) == 15);
    int fq = lane >> 4;                  // quarter 0..3 (when isfre)

    // update-phase ownership: j = tid>>2 (h row), f0 = (tid&3)*4 (f range)
    int j  = tid >> 2;
    int f0 = (tid & 3) * 4;

    if (tid < H_/2) h_p[tid] = 0u;
    if (tid < 16) {
        float ang = (float)tid * 0.39269908169872414f; // 2*pi/16
        cs_s[tid] = cosf(ang);
        sn_s[tid] = sinf(ang);
    }
    float Sre[4], Sim[4];
    #pragma unroll
    for (int r = 0; r < 4; ++r) { Sre[r] = 0.0f; Sim[r] = 0.0f; }

    float ba_j = b_a[j];
    float4 ua4 = ((const float4*)U_a)[tid & 3];
    const uint4* Uf = UF + (wid * 32 + fq * 8);   // quarter fq of fre col wid
    const float* Xb = X + (size_t)b * T_ * NCOL;
    __half* h_h = (__half*)h_p;

    float hnew = 0.0f;
    __syncthreads();

    for (int t = 0; t < T_; ++t) {
        const float* xrow = Xb + (size_t)t * NCOL;

        // ---- dot phase: pre[col=tid] = x + U[:,col] . h ----
        float acc = ntload_f(&xrow[tid]);
        #pragma unroll 8
        for (int kk = 0; kk < 32; ++kk) {
            uint4 u  = U8[kk * 1024 + tid];
            uint4 hp = *(const uint4*)&h_p[kk * 4];
            acc = dot2(u.x, hp.x, acc);
            acc = dot2(u.y, hp.y, acc);
            acc = dot2(u.z, hp.z, acc);
            acc = dot2(u.w, hp.w, acc);
        }
        float fa = 0.0f;
        if (isfre) {
            #pragma unroll
            for (int q = 0; q < 8; ++q) {
                uint4 u  = Uf[q];
                uint4 hp = *(const uint4*)&h_p[fq * 32 + q * 4];
                fa = dot2(u.x, hp.x, fa);
                fa = dot2(u.y, hp.y, fa);
                fa = dot2(u.z, hp.z, fa);
                fa = dot2(u.w, hp.w, fa);
            }
        }
        pre_s[tid] = acc;
        if (isfre) qp[wid*4 + fq] = fa;
        __syncthreads();   // A: pre_s + qp ready; h reads done

        // ---- update phase ----
        float xi   = pre_s[j];
        float xste = pre_s[256 + j];
        float xc   = pre_s[512 + j];
        float xo   = pre_s[768 + j];
        float gi   = hsig(xi);
        float gste = hsig(xste);
        float go   = hsig(xo);
        float cc   = gi * tanhf(xc);

        float4 xfre = ntload_f4(&xrow[1024 + f0]);
        float4 q0 = *(const float4*)&qp[(f0+0)*4];
        float4 q1 = *(const float4*)&qp[(f0+1)*4];
        float4 q2 = *(const float4*)&qp[(f0+2)*4];
        float4 q3 = *(const float4*)&qp[(f0+3)*4];
        float fre[4];
        fre[0] = hsig(xfre.x + q0.x + q0.y + q0.z + q0.w);
        fre[1] = hsig(xfre.y + q1.x + q1.y + q1.z + q1.w);
        fre[2] = hsig(xfre.z + q2.x + q2.y + q2.z + q2.w);
        fre[3] = hsig(xfre.w + q3.x + q3.y + q3.z + q3.w);

        int tt1 = (t + 1) & 15;
        float Aa = 0.0f;
        #pragma unroll
        for (int r = 0; r < 4; ++r) {
            int idx = (tt1 * (f0 + r)) & 15;
            float dec = gste * fre[r];
            float sre = fmaf(dec, Sre[r], cc * cs_s[idx]);
            float sim = fmaf(dec, Sim[r], cc * sn_s[idx]);
            Sre[r] = sre; Sim[r] = sim;
            Aa = fmaf(fmaf(sre, sre, sim*sim), ((const float*)&ua4)[r], Aa);
        }
        Aa += __shfl_xor(Aa, 1);
        Aa += __shfl_xor(Aa, 2);
        if ((tid & 3) == 0) {
            float a = tanhf(Aa + ba_j);
            hnew = go * a;
            h_h[j] = __float2half(hnew);
        }
        __syncthreads();   // B: h ready; pre_s/qp reads done
    }

    // ---- head: out[b] = (sum_j h[j]*W_p[j] + b_p)*fc_w + fc_b ----
    if ((tid & 3) == 0) pre_s[j] = hnew * W_p[j];
    __syncthreads();
    for (int s = 128; s > 0; s >>= 1) {
        if (tid < s) pre_s[tid] += pre_s[tid + s];
        __syncthreads();
    }
    if (tid == 0) out[b] = (pre_s[0] + b_p[0]) * fc_w[0] + fc_b[0];
}

// ---------------------------------------------------------------------------
extern "C" void kernel_launch(void* const* d_in, const int* in_sizes, int n_in,
                              void* d_out, int out_size, void* d_ws, size_t ws_size,
                              hipStream_t stream) {
    const float* signal = (const float*)d_in[0];
    const float* metmast = (const float*)d_in[1];
    const float* W_i_s   = (const float*)d_in[2];
    const float* W_ste_s = (const float*)d_in[3];
    const float* W_fre_s = (const float*)d_in[4];
    const float* W_c_s   = (const float*)d_in[5];
    const float* W_o_s   = (const float*)d_in[6];
    const float* W_i_m   = (const float*)d_in[7];
    const float* W_ste_m = (const float*)d_in[8];
    const float* W_fre_m = (const float*)d_in[9];
    const float* W_c_m   = (const float*)d_in[10];
    const float* W_o_m   = (const float*)d_in[11];
    const float* U_i   = (const float*)d_in[12];
    const float* b_i   = (const float*)d_in[13];
    const float* U_ste = (const float*)d_in[14];
    const float* b_ste = (const float*)d_in[15];
    const float* U_fre = (const float*)d_in[16];
    const float* b_fre = (const float*)d_in[17];
    const float* U_c   = (const float*)d_in[18];
    const float* b_c   = (const float*)d_in[19];
    const float* U_o   = (const float*)d_in[20];
    const float* b_o   = (const float*)d_in[21];
    const float* U_a   = (const float*)d_in[22];
    const float* b_a   = (const float*)d_in[23];
    const float* W_p   = (const float*)d_in[24];
    const float* b_p   = (const float*)d_in[25];
    const float* fc_w  = (const float*)d_in[26];
    const float* fc_b  = (const float*)d_in[27];
    float* out = (float*)d_out;

    char* ws = (char*)d_ws;
    float*          Wcat = (float*)(ws + 0);                 //  96*1040*4 = 399360
    float*          bcat = (float*)(ws + 399360);            //  1040*4    = 4160
    unsigned short* U8   = (unsigned short*)(ws + 403520);   //  1024*256*2 = 524288
    unsigned short* UF   = (unsigned short*)(ws + 927808);   //  16*256*2   = 8192
    float*          X    = (float*)(ws + 936000);            //  256*128*1040*4 = 136314880
    // total ~137.3 MB

    pack_kernel<<<256, 256, 0, stream>>>(
        W_i_s, W_ste_s, W_fre_s, W_c_s, W_o_s,
        W_i_m, W_ste_m, W_fre_m, W_c_m, W_o_m,
        U_i, U_ste, U_fre, U_c, U_o,
        b_i, b_ste, b_fre, b_c, b_o,
        Wcat, bcat, U8, UF);

    proj_kernel<<<dim3(9, 32, 8), 256, 0, stream>>>(signal, metmast, Wcat, bcat, X);

    recur_kernel<<<B_, 1024, 0, stream>>>(X, (const uint4*)U8, (const uint4*)UF,
                                          U_a, b_a, W_p, b_p, fc_w, fc_b, out);
}